// Round 7
// baseline (445.790 us; speedup 1.0000x reference)
//
#include <hip/hip_runtime.h>
#include <hip/hip_bf16.h>

#define L_SEQ 32
#define DIM 128
#define NN 50000

typedef __attribute__((ext_vector_type(8))) short bf16x8s;
typedef __attribute__((ext_vector_type(4))) float f32x4;

// ---------- helpers ----------
__device__ __forceinline__ float bf2f(short s){
    union{unsigned u; float f;} v; v.u = ((unsigned)(unsigned short)s) << 16; return v.f;
}
__device__ __forceinline__ short f2bf(float x){
    union{__hip_bfloat16 h; short s;} u; u.h = __float2bfloat16(x); return u.s;
}
__device__ __forceinline__ void ldf8(const float* p, float* w){
    const float4 a = *reinterpret_cast<const float4*>(p);
    const float4 b = *reinterpret_cast<const float4*>(p+4);
    w[0]=a.x; w[1]=a.y; w[2]=a.z; w[3]=a.w;
    w[4]=b.x; w[5]=b.y; w[6]=b.z; w[7]=b.w;
}
__device__ __forceinline__ void st8bf(short* dst, const float* v){
    union{ short s[8]; uint4 q; } u;
    #pragma unroll
    for (int i=0;i<8;++i) u.s[i] = f2bf(v[i]);
    *reinterpret_cast<uint4*>(dst) = u.q;
}
__device__ __forceinline__ bf16x8s cvt8(const float* v){
    union{ short s[8]; bf16x8s b; } u;
    #pragma unroll
    for (int i=0;i<8;++i) u.s[i] = f2bf(v[i]);
    return u.b;
}
__device__ __forceinline__ float sigmoidf(float x){ return 1.0f/(1.0f+__expf(-x)); }
__device__ __forceinline__ float tanh_fast(float x){
    x = fminf(fmaxf(x, -15.f), 15.f);
    float e = __expf(2.f*x);
    return (e-1.f)/(e+1.f);
}
__device__ __forceinline__ f32x4 mfma16(bf16x8s a, bf16x8s b, f32x4 c){
    return __builtin_amdgcn_mfma_f32_16x16x32_bf16(a, b, c, 0, 0, 0);
}

// ---------- fused prologue: weight transpose->bf16, emb->bf16 ----------
// blocks [0,1344): transp | [1344,4469): emb2bf
// wt element offsets: WinT 0 [128][128] | WoutT 16384 | WaT 32768 [384][256] |
// UhT 131072 [384][128] | WiT 180224 | WhT 229376 | W1T 278528 | W2T 294912 |
// W3T 311296 [128][256]   total 344064
__global__ __launch_bounds__(256)
void prep_kernel(const float* __restrict__ W_in, const float* __restrict__ W_out,
                 const float* __restrict__ W_a,  const float* __restrict__ U_h,
                 const float* __restrict__ Wi,   const float* __restrict__ Wh,
                 const float* __restrict__ W1,   const float* __restrict__ W2,
                 const float* __restrict__ W3,   short* __restrict__ wt,
                 const float* __restrict__ emb,  short* __restrict__ embf)
{
    const int blk = blockIdx.x;
    if (blk < 1344) {
        int idx = blk*256 + threadIdx.x;
        const float* src; int Rm1, lR, C, local, off;
        if      (idx < 16384) { src=W_in;  local=idx;        off=0;      Rm1=127; lR=7; C=128; }
        else if (idx < 32768) { src=W_out; local=idx-16384;  off=16384;  Rm1=127; lR=7; C=128; }
        else if (idx < 131072){ src=W_a;   local=idx-32768;  off=32768;  Rm1=255; lR=8; C=384; }
        else if (idx < 180224){ src=U_h;   local=idx-131072; off=131072; Rm1=127; lR=7; C=384; }
        else if (idx < 229376){ src=Wi;    local=idx-180224; off=180224; Rm1=127; lR=7; C=384; }
        else if (idx < 278528){ src=Wh;    local=idx-229376; off=229376; Rm1=127; lR=7; C=384; }
        else if (idx < 294912){ src=W1;    local=idx-278528; off=278528; Rm1=127; lR=7; C=128; }
        else if (idx < 311296){ src=W2;    local=idx-294912; off=294912; Rm1=127; lR=7; C=128; }
        else if (idx < 344064){ src=W3;    local=idx-311296; off=311296; Rm1=255; lR=8; C=128; }
        else return;
        int r = local & Rm1;      // k (dst inner)
        int c = local >> lR;      // n (dst row)
        wt[off + local] = f2bf(src[r*C + c]);
    } else {
        const size_t idx = ((size_t)(blk-1344)*256 + threadIdx.x) * 8;   // 3125*256*8 == NN*DIM
        float v[8]; ldf8(emb + idx, v);
        st8bf(embf + idx, v);
    }
}

// ---------- fused graph kernel: one block (4 waves) per session, MFMA ----------
// LDS: s_h 8704 + s_a 16896 + s_r3 8704 + s_r4 17408 = 51712 B -> 3 blocks/CU
// (round-4 verified-best form; 4-blocks/CU arena variant measured neutral in R6)
#define LDH 136   // 128-wide bf16 rows, +8 pad (272 B, 16B-aligned rows)
#define LDA 264   // 256-wide (+8 pad; conflict-free, 16B-aligned)
#define LDT 40    // transposed k<=32 rows (80 B, 16B-aligned)

__global__ __launch_bounds__(256)
void graph_fused(const int* __restrict__ items,
                 const float* __restrict__ A_in, const float* __restrict__ A_out,
                 const float* __restrict__ inter,
                 const int* __restrict__ seq_len,
                 const float* __restrict__ emb,
                 const short* __restrict__ embf,   // bf16 emb copy (may be null)
                 const float* __restrict__ b_in, const float* __restrict__ b_out,
                 const float* __restrict__ b_gru,
                 const float* __restrict__ bi, const float* __restrict__ bh,
                 const float* __restrict__ b1, const float* __restrict__ b2,
                 const float* __restrict__ wq, const float* __restrict__ bq,
                 const float* __restrict__ b3,
                 const short* __restrict__ wt,
                 short* __restrict__ hs_bf)
{
    const short* WinT  = wt + 0;
    const short* WoutT = wt + 16384;
    const short* WaT   = wt + 32768;
    const short* UhT   = wt + 131072;
    const short* WiT   = wt + 180224;
    const short* WhT   = wt + 229376;
    const short* W1T   = wt + 278528;
    const short* W2T   = wt + 294912;
    const short* W3T   = wt + 311296;

    __shared__ __align__(16) short s_h[32*LDH];        // h (bf16, A-layout)      8704 B
    __shared__ __align__(16) short s_a[32*LDA];        // concat(a_in,a_out)     16896 B
    __shared__ __align__(16) short s_r3[32*LDH];       // {Ain,Aout} then intra   8704 B
    __shared__ __align__(16) short s_r4[2*32*LDH];     // xT then {inter,final}  17408 B

    short* s_Ain  = s_r3;               // 32*40
    short* s_Aout = s_r3 + 32*LDT;      // 32*40
    short* s_x    = s_r3;               // intra, 32*136 (after step2)
    short* xT     = s_r4;               // 128*40 (single buffer, two passes)
    short* s_int  = s_r4;               // inter, 32*136 (after step2b)
    short* s_fin  = s_r4 + 32*LDH;      // final, 32*136
    // epilogue float scratch aliased onto s_a (s_a dead after step4)
    float* s_vn    = (float*)s_a;           // 128
    float* s_q1    = s_vn + 128;            // 128
    float* s_sg    = s_q1 + 128;            // 128
    float* s_red   = s_sg + 128;            // 256
    float* s_alpha = s_red + 256;           // 32

    const int b    = blockIdx.x;
    const int t    = threadIdx.x;
    const int wave = t >> 6;
    const int lane = t & 63;
    const int quad = lane >> 4;
    const int lc   = lane & 15;
    const int kq   = quad * 8;

    // ---- step0: fp32 inter prefetch to regs (committed at step3); h gather + A -> LDS
    float pre_i[2][8];
    #pragma unroll
    for (int i=0;i<2;++i) {
        int c = t + i*256;
        int l = c >> 4, k = (c & 15) * 8;
        ldf8(inter + ((size_t)b*L_SEQ + l)*DIM + k, pre_i[i]);
    }
    if (embf) {
        #pragma unroll
        for (int i=0;i<2;++i) {
            int c = t + i*256;                 // 512 chunks of 8 shorts (16 B)
            int l = c >> 4, k = (c & 15) * 8;
            int it = items[b*L_SEQ + l];
            *reinterpret_cast<uint4*>(&s_h[l*LDH + k]) =
                *reinterpret_cast<const uint4*>(embf + (size_t)it*DIM + k);
        }
    } else {
        #pragma unroll
        for (int i=0;i<2;++i) {
            int c = t + i*256;
            int l = c >> 4, k = (c & 15) * 8;
            int it = items[b*L_SEQ + l];
            float v[8]; ldf8(emb + (size_t)it*DIM + k, v);
            st8bf(&s_h[l*LDH + k], v);
        }
    }
    {
        const int which = t >> 7;
        const int rem   = t & 127;
        const int l = rem >> 2, m = (rem & 3) * 8;
        const float* src = which ? A_out : A_in;
        float v[8]; ldf8(src + b*L_SEQ*L_SEQ + l*L_SEQ + m, v);
        st8bf((which ? s_Aout : s_Ain) + l*LDT + m, v);
    }
    __syncthreads();

    // ---- step1/step2 two passes over op (shared xT buffer)
    #pragma unroll
    for (int op = 0; op < 2; ++op) {
        // step1: h @ {W_in|W_out} + bias -> xT[n][k]
        const short* WT_ = op ? WoutT : WinT;
        #pragma unroll
        for (int p = 0; p < 2; ++p) {
            const int nt = wave*2 + p;
            const int n  = nt*16 + lc;
            const float bv = op ? b_out[n] : b_in[n];
            f32x4 acc0 = {bv,bv,bv,bv}, acc1 = {bv,bv,bv,bv};
            #pragma unroll
            for (int ks = 0; ks < 4; ++ks) {
                const int ko = ks*32 + kq;
                bf16x8s bb = *(const bf16x8s*)(WT_ + n*128 + ko);
                bf16x8s a0 = *(const bf16x8s*)(&s_h[(lc   )*LDH + ko]);
                bf16x8s a1 = *(const bf16x8s*)(&s_h[(16+lc)*LDH + ko]);
                acc0 = mfma16(a0, bb, acc0);
                acc1 = mfma16(a1, bb, acc1);
            }
            union{short s[4]; unsigned long long q;} u0, u1;
            #pragma unroll
            for (int i=0;i<4;++i){ u0.s[i]=f2bf(acc0[i]); u1.s[i]=f2bf(acc1[i]); }
            *(unsigned long long*)(&xT[n*LDT + 0  + quad*4]) = u0.q;
            *(unsigned long long*)(&xT[n*LDT + 16 + quad*4]) = u1.q;
        }
        __syncthreads();
        // step2: {A_in|A_out} @ xT -> s_a half (K=32, one MFMA per unit)
        const short* Abuf = op ? s_Aout : s_Ain;
        #pragma unroll
        for (int u = 0; u < 4; ++u) {
            int unit = wave*4 + u;             // 0..15
            int nt = unit >> 1, m0 = (unit & 1)*16;
            bf16x8s a  = *(const bf16x8s*)(&Abuf[(m0+lc)*LDT + kq]);
            bf16x8s bb = *(const bf16x8s*)(&xT[(nt*16+lc)*LDT + kq]);
            f32x4 acc = {0.f,0.f,0.f,0.f};
            acc = mfma16(a, bb, acc);
            #pragma unroll
            for (int i=0;i<4;++i)
                s_a[(m0+quad*4+i)*LDA + op*128 + nt*16 + lc] = f2bf(acc[i]);
        }
        __syncthreads();
    }

    // ---- step3: commit prefetched inter -> s_int (xT dead after last barrier)
    #pragma unroll
    for (int i=0;i<2;++i) {
        int c = t + i*256;
        int l = c >> 4, k = (c & 15) * 8;
        st8bf(&s_int[l*LDH + k], pre_i[i]);
    }

    // ---- step4: intra = GRU(a@W_a + b_gru, h@U_h ; h) -> s_x
    #pragma unroll
    for (int g = wave; g < 8; g += 4) {
        const int n = g*16 + lc;
        const float vr = b_gru[n], vz = b_gru[128+n], vn2 = b_gru[256+n];
        f32x4 ar[2], az[2], an[2], pr[2], pz[2], pn[2];
        #pragma unroll
        for (int m=0;m<2;++m){
            ar[m]=(f32x4){vr,vr,vr,vr}; az[m]=(f32x4){vz,vz,vz,vz}; an[m]=(f32x4){vn2,vn2,vn2,vn2};
            pr[m]=(f32x4){0,0,0,0}; pz[m]=pr[m]; pn[m]=pr[m];
        }
        #pragma unroll
        for (int ks=0; ks<8; ++ks) {
            const int ko = ks*32 + kq;
            bf16x8s br = *(const bf16x8s*)(WaT + (n      )*256 + ko);
            bf16x8s bz = *(const bf16x8s*)(WaT + (n + 128)*256 + ko);
            bf16x8s bn = *(const bf16x8s*)(WaT + (n + 256)*256 + ko);
            #pragma unroll
            for (int m=0;m<2;++m){
                bf16x8s a = *(const bf16x8s*)(&s_a[(m*16+lc)*LDA + ko]);
                ar[m]=mfma16(a,br,ar[m]); az[m]=mfma16(a,bz,az[m]); an[m]=mfma16(a,bn,an[m]);
            }
        }
        #pragma unroll
        for (int ks=0; ks<4; ++ks) {
            const int ko = ks*32 + kq;
            bf16x8s br = *(const bf16x8s*)(UhT + (n      )*128 + ko);
            bf16x8s bz = *(const bf16x8s*)(UhT + (n + 128)*128 + ko);
            bf16x8s bn = *(const bf16x8s*)(UhT + (n + 256)*128 + ko);
            #pragma unroll
            for (int m=0;m<2;++m){
                bf16x8s a = *(const bf16x8s*)(&s_h[(m*16+lc)*LDH + ko]);
                pr[m]=mfma16(a,br,pr[m]); pz[m]=mfma16(a,bz,pz[m]); pn[m]=mfma16(a,bn,pn[m]);
            }
        }
        #pragma unroll
        for (int m=0;m<2;++m)
        #pragma unroll
        for (int i=0;i<4;++i){
            const int row = m*16 + quad*4 + i;
            float hp = bf2f(s_h[row*LDH + n]);
            float r  = sigmoidf(ar[m][i] + pr[m][i]);
            float z  = sigmoidf(az[m][i] + pz[m][i]);
            float nn = tanh_fast(an[m][i] + r*pn[m][i]);
            s_x[row*LDH + n] = f2bf((1.f - z)*nn + z*hp);
        }
    }
    __syncthreads();

    // ---- step6: final = GRU(intra@Wi + bi, inter@Wh + bh ; inter) -> s_fin
    #pragma unroll
    for (int g = wave; g < 8; g += 4) {
        const int n = g*16 + lc;
        const float vir = bi[n], viz = bi[128+n], vin = bi[256+n];
        const float vhr = bh[n], vhz = bh[128+n], vhn = bh[256+n];
        f32x4 ar[2], az[2], an[2], pr[2], pz[2], pn[2];
        #pragma unroll
        for (int m=0;m<2;++m){
            ar[m]=(f32x4){vir,vir,vir,vir}; az[m]=(f32x4){viz,viz,viz,viz}; an[m]=(f32x4){vin,vin,vin,vin};
            pr[m]=(f32x4){vhr,vhr,vhr,vhr}; pz[m]=(f32x4){vhz,vhz,vhz,vhz}; pn[m]=(f32x4){vhn,vhn,vhn,vhn};
        }
        #pragma unroll
        for (int ks=0; ks<4; ++ks) {
            const int ko = ks*32 + kq;
            bf16x8s br = *(const bf16x8s*)(WiT + (n      )*128 + ko);
            bf16x8s bz = *(const bf16x8s*)(WiT + (n + 128)*128 + ko);
            bf16x8s bn = *(const bf16x8s*)(WiT + (n + 256)*128 + ko);
            #pragma unroll
            for (int m=0;m<2;++m){
                bf16x8s a = *(const bf16x8s*)(&s_x[(m*16+lc)*LDH + ko]);
                ar[m]=mfma16(a,br,ar[m]); az[m]=mfma16(a,bz,az[m]); an[m]=mfma16(a,bn,an[m]);
            }
        }
        #pragma unroll
        for (int ks=0; ks<4; ++ks) {
            const int ko = ks*32 + kq;
            bf16x8s br = *(const bf16x8s*)(WhT + (n      )*128 + ko);
            bf16x8s bz = *(const bf16x8s*)(WhT + (n + 128)*128 + ko);
            bf16x8s bn = *(const bf16x8s*)(WhT + (n + 256)*128 + ko);
            #pragma unroll
            for (int m=0;m<2;++m){
                bf16x8s a = *(const bf16x8s*)(&s_int[(m*16+lc)*LDH + ko]);
                pr[m]=mfma16(a,br,pr[m]); pz[m]=mfma16(a,bz,pz[m]); pn[m]=mfma16(a,bn,pn[m]);
            }
        }
        #pragma unroll
        for (int m=0;m<2;++m)
        #pragma unroll
        for (int i=0;i<4;++i){
            const int row = m*16 + quad*4 + i;
            float hp = bf2f(s_int[row*LDH + n]);
            float r  = sigmoidf(ar[m][i] + pr[m][i]);
            float z  = sigmoidf(az[m][i] + pz[m][i]);
            float nn = tanh_fast(an[m][i] + r*pn[m][i]);
            s_fin[row*LDH + n] = f2bf((1.f - z)*nn + z*hp);
        }
    }
    __syncthreads();

    // ---- step7: attention readout (float scratch lives in s_a, dead since step4)
    const int slen = seq_len[b];
    if (t < DIM) s_vn[t] = bf2f(s_fin[(slen-1)*LDH + t]);
    __syncthreads();
    if (t < DIM) {                       // q1+b2 -> s_q1
        float acc = b1[t] + b2[t];
        #pragma unroll
        for (int k8=0; k8<16; ++k8) {
            union{ uint4 q; short s[8]; } u;
            u.q = *reinterpret_cast<const uint4*>(W1T + t*128 + k8*8);
            #pragma unroll
            for (int u2=0;u2<8;++u2) acc += s_vn[k8*8+u2]*bf2f(u.s[u2]);
        }
        s_q1[t] = acc;
    }
    __syncthreads();
    // final@W2 via MFMA; alpha partials
    #pragma unroll
    for (int tl = wave; tl < 16; tl += 4) {
        const int m0 = (tl & 1)*16, nt = tl >> 1;
        const int n  = nt*16 + lc;
        f32x4 acc = {0.f,0.f,0.f,0.f};
        #pragma unroll
        for (int ks=0; ks<4; ++ks) {
            const int ko = ks*32 + kq;
            bf16x8s a  = *(const bf16x8s*)(&s_fin[(m0+lc)*LDH + ko]);
            bf16x8s bb = *(const bf16x8s*)(W2T + n*128 + ko);
            acc = mfma16(a, bb, acc);
        }
        const float qb  = s_q1[n];
        const float wqv = wq[n];
        float p[4];
        #pragma unroll
        for (int i=0;i<4;++i) p[i] = sigmoidf(acc[i] + qb) * wqv;
        #pragma unroll
        for (int off=1; off<16; off<<=1) {
            #pragma unroll
            for (int i=0;i<4;++i) p[i] += __shfl_xor(p[i], off);
        }
        if (lc == 0) {
            #pragma unroll
            for (int i=0;i<4;++i) s_red[(m0+quad*4+i)*8 + nt] = p[i];
        }
    }
    __syncthreads();
    if (t < L_SEQ) {
        float al = bq[0];
        #pragma unroll
        for (int u=0;u<8;++u) al += s_red[t*8+u];
        s_alpha[t] = (t < slen) ? al : 0.f;
    }
    __syncthreads();
    if (t < DIM) {
        float sg = 0.f;
        #pragma unroll
        for (int l=0;l<L_SEQ;++l) sg += s_alpha[l]*bf2f(s_fin[l*LDH + t]);
        s_sg[t] = sg;
    }
    __syncthreads();
    if (t < DIM) {                       // h_s = concat(vn,sg)@W3 + b3 -> bf16
        float acc = b3[t];
        #pragma unroll
        for (int k8=0; k8<16; ++k8) {
            union{ uint4 q; short s[8]; } u;
            u.q = *reinterpret_cast<const uint4*>(W3T + t*256 + k8*8);
            #pragma unroll
            for (int u2=0;u2<8;++u2) acc += s_vn[k8*8+u2]*bf2f(u.s[u2]);
        }
        #pragma unroll
        for (int k8=0; k8<16; ++k8) {
            union{ uint4 q; short s[8]; } u;
            u.q = *reinterpret_cast<const uint4*>(W3T + t*256 + 128 + k8*8);
            #pragma unroll
            for (int u2=0;u2<8;++u2) acc += s_sg[k8*8+u2]*bf2f(u.s[u2]);
        }
        hs_bf[b*DIM + t] = f2bf(acc);
    }
}

// ---------- scores = h_s @ emb^T, bf16 emb (round-4 form; SINGLE CHANGE: plain
// cached stores instead of nontemporal -> let L2 merge the four adjacent-nt 64B
// row-segments into full lines before HBM writeback) ----------
// grid (782, 4); wave owns 64 m-rows (4 hoisted A-frag sets), 64 n-cols.
__global__ __launch_bounds__(256)
void scores_bf(const short* __restrict__ hs, const short* __restrict__ embf,
               float* __restrict__ out)
{
    const int t    = threadIdx.x;
    const int wave = t >> 6;
    const int lane = t & 63;
    const int quad = lane >> 4;
    const int lc   = lane & 15;
    const int kq   = quad * 8;
    const int n0   = blockIdx.x * 64;
    const int mb   = blockIdx.y * 256 + wave*64;   // this wave's 64 rows

    bf16x8s hf[4][4];                              // hoisted hs fragments (L2-hot)
    #pragma unroll
    for (int mi=0; mi<4; ++mi)
        #pragma unroll
        for (int ks=0; ks<4; ++ks)
            hf[mi][ks] = *(const bf16x8s*)(hs + (size_t)(mb + mi*16 + lc)*DIM + ks*32 + kq);

    #pragma unroll
    for (int nt=0; nt<4; ++nt) {
        const int nr  = n0 + nt*16 + lc;
        const int nld = nr < NN ? nr : NN-1;
        bf16x8s ef[4];
        #pragma unroll
        for (int ks=0; ks<4; ++ks)
            ef[ks] = *(const bf16x8s*)(embf + (size_t)nld*DIM + ks*32 + kq);
        const int nbase = n0 + nt*16 + quad*4;     // NN % 4 == 0 -> chunk validity uniform
        #pragma unroll
        for (int mi=0; mi<4; ++mi) {
            f32x4 acc = {0.f,0.f,0.f,0.f};
            #pragma unroll
            for (int ks=0; ks<4; ++ks) acc = mfma16(ef[ks], hf[mi][ks], acc);
            if (nbase < NN) {
                // D[r=quad*4+i][c=lc] = scores[mb+mi*16+lc][n0+nt*16+quad*4+i]
                *reinterpret_cast<f32x4*>(&out[(size_t)(mb + mi*16 + lc)*NN + nbase]) = acc;
            }
        }
    }
}

// ---------- fallback (fp32 emb) if workspace too small for bf16 copies ----------
__global__ __launch_bounds__(256)
void scores_kernel(const short* __restrict__ hs, const float* __restrict__ emb,
                   float* __restrict__ out)
{
    const int t    = threadIdx.x;
    const int wave = t >> 6;
    const int lane = t & 63;
    const int quad = lane >> 4;
    const int lc   = lane & 15;
    const int kq   = quad * 8;
    const int n0   = blockIdx.x * 64;
    const int m0   = blockIdx.y * 64 + wave*16;

    bf16x8s af[4];
    #pragma unroll
    for (int ks=0; ks<4; ++ks)
        af[ks] = *(const bf16x8s*)(hs + (size_t)(m0 + lc)*DIM + ks*32 + kq);

    #pragma unroll
    for (int nt=0; nt<4; ++nt) {
        const int nabs = n0 + nt*16 + lc;
        const int nld  = nabs < NN ? nabs : NN-1;
        f32x4 acc = {0.f,0.f,0.f,0.f};
        #pragma unroll
        for (int ks=0; ks<4; ++ks) {
            float v[8]; ldf8(emb + (size_t)nld*DIM + ks*32 + kq, v);
            acc = mfma16(af[ks], cvt8(v), acc);
        }
        if (nabs < NN) {
            #pragma unroll
            for (int i=0;i<4;++i)
                out[(size_t)(m0 + quad*4 + i)*NN + nabs] = acc[i];
        }
    }
}

extern "C" void kernel_launch(void* const* d_in, const int* in_sizes, int n_in,
                              void* d_out, int out_size, void* d_ws, size_t ws_size,
                              hipStream_t stream)
{
    const int*   items   = (const int*)  d_in[0];
    const float* A_in    = (const float*)d_in[1];
    const float* A_out   = (const float*)d_in[2];
    const float* inter   = (const float*)d_in[3];
    const int*   seq_len = (const int*)  d_in[4];
    const float* emb     = (const float*)d_in[5];
    const float* W_in = (const float*)d_in[6],  *b_in  = (const float*)d_in[7];
    const float* W_out= (const float*)d_in[8],  *b_out = (const float*)d_in[9];
    const float* W_a  = (const float*)d_in[10], *U_h   = (const float*)d_in[11];
    const float* b_gru= (const float*)d_in[12];
    const float* Wi   = (const float*)d_in[13], *bi    = (const float*)d_in[14];
    const float* Wh   = (const float*)d_in[15], *bh    = (const float*)d_in[16];
    const float* W1   = (const float*)d_in[17], *b1    = (const float*)d_in[18];
    const float* W2   = (const float*)d_in[19], *b2    = (const float*)d_in[20];
    const float* wq   = (const float*)d_in[21], *bq    = (const float*)d_in[22];
    const float* W3   = (const float*)d_in[23], *b3    = (const float*)d_in[24];
    float* out = (float*)d_out;
    short* hs_bf = (short*)d_ws;                           // 1024*128 bf16 = 256 KB
    short* wt    = (short*)((char*)d_ws + 262144);         // 344064 bf16 = 688 KB
    short* embf  = (short*)((char*)d_ws + 1048576);        // 50000*128 bf16 = 12.8 MB

    const size_t need_bf = 1048576 + (size_t)NN*DIM*2;     // ~13.85 MB
    const bool use_bf = (ws_size >= need_bf);

    prep_kernel<<<use_bf ? 4469 : 1344, 256, 0, stream>>>(
        W_in, W_out, W_a, U_h, Wi, Wh, W1, W2, W3, wt, emb, embf);
    graph_fused<<<1024, 256, 0, stream>>>(items, A_in, A_out, inter, seq_len, emb,
        use_bf ? embf : (const short*)nullptr,
        b_in, b_out, b_gru, bi, bh, b1, b2, wq, bq, b3, wt, hs_bf);
    if (use_bf)
        scores_bf<<<dim3(782, 4), 256, 0, stream>>>(hs_bf, embf, out);
    else
        scores_kernel<<<dim3(782, 16), 256, 0, stream>>>(hs_bf, emb, out);
}

// Round 8
// 402.676 us; speedup vs baseline: 1.1071x; 1.1071x over previous
//
#include <hip/hip_runtime.h>
#include <hip/hip_bf16.h>

#define L_SEQ 32
#define DIM 128
#define NN 50000

typedef __attribute__((ext_vector_type(8))) short bf16x8s;
typedef __attribute__((ext_vector_type(4))) float f32x4;

// ---------- helpers ----------
__device__ __forceinline__ float bf2f(short s){
    union{unsigned u; float f;} v; v.u = ((unsigned)(unsigned short)s) << 16; return v.f;
}
__device__ __forceinline__ short f2bf(float x){
    union{__hip_bfloat16 h; short s;} u; u.h = __float2bfloat16(x); return u.s;
}
__device__ __forceinline__ void ldf8(const float* p, float* w){
    const float4 a = *reinterpret_cast<const float4*>(p);
    const float4 b = *reinterpret_cast<const float4*>(p+4);
    w[0]=a.x; w[1]=a.y; w[2]=a.z; w[3]=a.w;
    w[4]=b.x; w[5]=b.y; w[6]=b.z; w[7]=b.w;
}
__device__ __forceinline__ void st8bf(short* dst, const float* v){
    union{ short s[8]; uint4 q; } u;
    #pragma unroll
    for (int i=0;i<8;++i) u.s[i] = f2bf(v[i]);
    *reinterpret_cast<uint4*>(dst) = u.q;
}
__device__ __forceinline__ bf16x8s cvt8(const float* v){
    union{ short s[8]; bf16x8s b; } u;
    #pragma unroll
    for (int i=0;i<8;++i) u.s[i] = f2bf(v[i]);
    return u.b;
}
__device__ __forceinline__ float sigmoidf(float x){ return 1.0f/(1.0f+__expf(-x)); }
__device__ __forceinline__ float tanh_fast(float x){
    x = fminf(fmaxf(x, -15.f), 15.f);
    float e = __expf(2.f*x);
    return (e-1.f)/(e+1.f);
}
__device__ __forceinline__ f32x4 mfma16(bf16x8s a, bf16x8s b, f32x4 c){
    return __builtin_amdgcn_mfma_f32_16x16x32_bf16(a, b, c, 0, 0, 0);
}

// ---------- fused prologue: weight transpose->bf16, emb->bf16 ----------
// blocks [0,1344): transp | [1344,4469): emb2bf
// wt element offsets: WinT 0 [128][128] | WoutT 16384 | WaT 32768 [384][256] |
// UhT 131072 [384][128] | WiT 180224 | WhT 229376 | W1T 278528 | W2T 294912 |
// W3T 311296 [128][256]   total 344064
__global__ __launch_bounds__(256)
void prep_kernel(const float* __restrict__ W_in, const float* __restrict__ W_out,
                 const float* __restrict__ W_a,  const float* __restrict__ U_h,
                 const float* __restrict__ Wi,   const float* __restrict__ Wh,
                 const float* __restrict__ W1,   const float* __restrict__ W2,
                 const float* __restrict__ W3,   short* __restrict__ wt,
                 const float* __restrict__ emb,  short* __restrict__ embf)
{
    const int blk = blockIdx.x;
    if (blk < 1344) {
        int idx = blk*256 + threadIdx.x;
        const float* src; int Rm1, lR, C, local, off;
        if      (idx < 16384) { src=W_in;  local=idx;        off=0;      Rm1=127; lR=7; C=128; }
        else if (idx < 32768) { src=W_out; local=idx-16384;  off=16384;  Rm1=127; lR=7; C=128; }
        else if (idx < 131072){ src=W_a;   local=idx-32768;  off=32768;  Rm1=255; lR=8; C=384; }
        else if (idx < 180224){ src=U_h;   local=idx-131072; off=131072; Rm1=127; lR=7; C=384; }
        else if (idx < 229376){ src=Wi;    local=idx-180224; off=180224; Rm1=127; lR=7; C=384; }
        else if (idx < 278528){ src=Wh;    local=idx-229376; off=229376; Rm1=127; lR=7; C=384; }
        else if (idx < 294912){ src=W1;    local=idx-278528; off=278528; Rm1=127; lR=7; C=128; }
        else if (idx < 311296){ src=W2;    local=idx-294912; off=294912; Rm1=127; lR=7; C=128; }
        else if (idx < 344064){ src=W3;    local=idx-311296; off=311296; Rm1=255; lR=8; C=128; }
        else return;
        int r = local & Rm1;      // k (dst inner)
        int c = local >> lR;      // n (dst row)
        wt[off + local] = f2bf(src[r*C + c]);
    } else {
        const size_t idx = ((size_t)(blk-1344)*256 + threadIdx.x) * 8;   // 3125*256*8 == NN*DIM
        float v[8]; ldf8(emb + idx, v);
        st8bf(embf + idx, v);
    }
}

// ---------- fused graph kernel: one block (4 waves) per session, MFMA ----------
// LDS: s_h 8704 + s_a 16896 + s_r3 8704 + s_r4 17408 = 51712 B -> 3 blocks/CU
// (round-4 verified-best form; 4-blocks/CU arena variant measured neutral)
#define LDH 136   // 128-wide bf16 rows, +8 pad (272 B, 16B-aligned rows)
#define LDA 264   // 256-wide (+8 pad; conflict-free, 16B-aligned)
#define LDT 40    // transposed k<=32 rows (80 B, 16B-aligned)

__global__ __launch_bounds__(256)
void graph_fused(const int* __restrict__ items,
                 const float* __restrict__ A_in, const float* __restrict__ A_out,
                 const float* __restrict__ inter,
                 const int* __restrict__ seq_len,
                 const float* __restrict__ emb,
                 const short* __restrict__ embf,   // bf16 emb copy (may be null)
                 const float* __restrict__ b_in, const float* __restrict__ b_out,
                 const float* __restrict__ b_gru,
                 const float* __restrict__ bi, const float* __restrict__ bh,
                 const float* __restrict__ b1, const float* __restrict__ b2,
                 const float* __restrict__ wq, const float* __restrict__ bq,
                 const float* __restrict__ b3,
                 const short* __restrict__ wt,
                 short* __restrict__ hs_bf)
{
    const short* WinT  = wt + 0;
    const short* WoutT = wt + 16384;
    const short* WaT   = wt + 32768;
    const short* UhT   = wt + 131072;
    const short* WiT   = wt + 180224;
    const short* WhT   = wt + 229376;
    const short* W1T   = wt + 278528;
    const short* W2T   = wt + 294912;
    const short* W3T   = wt + 311296;

    __shared__ __align__(16) short s_h[32*LDH];        // h (bf16, A-layout)      8704 B
    __shared__ __align__(16) short s_a[32*LDA];        // concat(a_in,a_out)     16896 B
    __shared__ __align__(16) short s_r3[32*LDH];       // {Ain,Aout} then intra   8704 B
    __shared__ __align__(16) short s_r4[2*32*LDH];     // xT then {inter,final}  17408 B

    short* s_Ain  = s_r3;               // 32*40
    short* s_Aout = s_r3 + 32*LDT;      // 32*40
    short* s_x    = s_r3;               // intra, 32*136 (after step2)
    short* xT     = s_r4;               // 128*40 (single buffer, two passes)
    short* s_int  = s_r4;               // inter, 32*136 (after step2b)
    short* s_fin  = s_r4 + 32*LDH;      // final, 32*136
    // epilogue float scratch aliased onto s_a (s_a dead after step4)
    float* s_vn    = (float*)s_a;           // 128
    float* s_q1    = s_vn + 128;            // 128
    float* s_sg    = s_q1 + 128;            // 128
    float* s_red   = s_sg + 128;            // 256
    float* s_alpha = s_red + 256;           // 32

    const int b    = blockIdx.x;
    const int t    = threadIdx.x;
    const int wave = t >> 6;
    const int lane = t & 63;
    const int quad = lane >> 4;
    const int lc   = lane & 15;
    const int kq   = quad * 8;

    // ---- step0: fp32 inter prefetch to regs (committed at step3); h gather + A -> LDS
    float pre_i[2][8];
    #pragma unroll
    for (int i=0;i<2;++i) {
        int c = t + i*256;
        int l = c >> 4, k = (c & 15) * 8;
        ldf8(inter + ((size_t)b*L_SEQ + l)*DIM + k, pre_i[i]);
    }
    if (embf) {
        #pragma unroll
        for (int i=0;i<2;++i) {
            int c = t + i*256;                 // 512 chunks of 8 shorts (16 B)
            int l = c >> 4, k = (c & 15) * 8;
            int it = items[b*L_SEQ + l];
            *reinterpret_cast<uint4*>(&s_h[l*LDH + k]) =
                *reinterpret_cast<const uint4*>(embf + (size_t)it*DIM + k);
        }
    } else {
        #pragma unroll
        for (int i=0;i<2;++i) {
            int c = t + i*256;
            int l = c >> 4, k = (c & 15) * 8;
            int it = items[b*L_SEQ + l];
            float v[8]; ldf8(emb + (size_t)it*DIM + k, v);
            st8bf(&s_h[l*LDH + k], v);
        }
    }
    {
        const int which = t >> 7;
        const int rem   = t & 127;
        const int l = rem >> 2, m = (rem & 3) * 8;
        const float* src = which ? A_out : A_in;
        float v[8]; ldf8(src + b*L_SEQ*L_SEQ + l*L_SEQ + m, v);
        st8bf((which ? s_Aout : s_Ain) + l*LDT + m, v);
    }
    __syncthreads();

    // ---- step1/step2 two passes over op (shared xT buffer)
    #pragma unroll
    for (int op = 0; op < 2; ++op) {
        // step1: h @ {W_in|W_out} + bias -> xT[n][k]
        const short* WT_ = op ? WoutT : WinT;
        #pragma unroll
        for (int p = 0; p < 2; ++p) {
            const int nt = wave*2 + p;
            const int n  = nt*16 + lc;
            const float bv = op ? b_out[n] : b_in[n];
            f32x4 acc0 = {bv,bv,bv,bv}, acc1 = {bv,bv,bv,bv};
            #pragma unroll
            for (int ks = 0; ks < 4; ++ks) {
                const int ko = ks*32 + kq;
                bf16x8s bb = *(const bf16x8s*)(WT_ + n*128 + ko);
                bf16x8s a0 = *(const bf16x8s*)(&s_h[(lc   )*LDH + ko]);
                bf16x8s a1 = *(const bf16x8s*)(&s_h[(16+lc)*LDH + ko]);
                acc0 = mfma16(a0, bb, acc0);
                acc1 = mfma16(a1, bb, acc1);
            }
            union{short s[4]; unsigned long long q;} u0, u1;
            #pragma unroll
            for (int i=0;i<4;++i){ u0.s[i]=f2bf(acc0[i]); u1.s[i]=f2bf(acc1[i]); }
            *(unsigned long long*)(&xT[n*LDT + 0  + quad*4]) = u0.q;
            *(unsigned long long*)(&xT[n*LDT + 16 + quad*4]) = u1.q;
        }
        __syncthreads();
        // step2: {A_in|A_out} @ xT -> s_a half (K=32, one MFMA per unit)
        const short* Abuf = op ? s_Aout : s_Ain;
        #pragma unroll
        for (int u = 0; u < 4; ++u) {
            int unit = wave*4 + u;             // 0..15
            int nt = unit >> 1, m0 = (unit & 1)*16;
            bf16x8s a  = *(const bf16x8s*)(&Abuf[(m0+lc)*LDT + kq]);
            bf16x8s bb = *(const bf16x8s*)(&xT[(nt*16+lc)*LDT + kq]);
            f32x4 acc = {0.f,0.f,0.f,0.f};
            acc = mfma16(a, bb, acc);
            #pragma unroll
            for (int i=0;i<4;++i)
                s_a[(m0+quad*4+i)*LDA + op*128 + nt*16 + lc] = f2bf(acc[i]);
        }
        __syncthreads();
    }

    // ---- step3: commit prefetched inter -> s_int (xT dead after last barrier)
    #pragma unroll
    for (int i=0;i<2;++i) {
        int c = t + i*256;
        int l = c >> 4, k = (c & 15) * 8;
        st8bf(&s_int[l*LDH + k], pre_i[i]);
    }

    // ---- step4: intra = GRU(a@W_a + b_gru, h@U_h ; h) -> s_x
    #pragma unroll
    for (int g = wave; g < 8; g += 4) {
        const int n = g*16 + lc;
        const float vr = b_gru[n], vz = b_gru[128+n], vn2 = b_gru[256+n];
        f32x4 ar[2], az[2], an[2], pr[2], pz[2], pn[2];
        #pragma unroll
        for (int m=0;m<2;++m){
            ar[m]=(f32x4){vr,vr,vr,vr}; az[m]=(f32x4){vz,vz,vz,vz}; an[m]=(f32x4){vn2,vn2,vn2,vn2};
            pr[m]=(f32x4){0,0,0,0}; pz[m]=pr[m]; pn[m]=pr[m];
        }
        #pragma unroll
        for (int ks=0; ks<8; ++ks) {
            const int ko = ks*32 + kq;
            bf16x8s br = *(const bf16x8s*)(WaT + (n      )*256 + ko);
            bf16x8s bz = *(const bf16x8s*)(WaT + (n + 128)*256 + ko);
            bf16x8s bn = *(const bf16x8s*)(WaT + (n + 256)*256 + ko);
            #pragma unroll
            for (int m=0;m<2;++m){
                bf16x8s a = *(const bf16x8s*)(&s_a[(m*16+lc)*LDA + ko]);
                ar[m]=mfma16(a,br,ar[m]); az[m]=mfma16(a,bz,az[m]); an[m]=mfma16(a,bn,an[m]);
            }
        }
        #pragma unroll
        for (int ks=0; ks<4; ++ks) {
            const int ko = ks*32 + kq;
            bf16x8s br = *(const bf16x8s*)(UhT + (n      )*128 + ko);
            bf16x8s bz = *(const bf16x8s*)(UhT + (n + 128)*128 + ko);
            bf16x8s bn = *(const bf16x8s*)(UhT + (n + 256)*128 + ko);
            #pragma unroll
            for (int m=0;m<2;++m){
                bf16x8s a = *(const bf16x8s*)(&s_h[(m*16+lc)*LDH + ko]);
                pr[m]=mfma16(a,br,pr[m]); pz[m]=mfma16(a,bz,pz[m]); pn[m]=mfma16(a,bn,pn[m]);
            }
        }
        #pragma unroll
        for (int m=0;m<2;++m)
        #pragma unroll
        for (int i=0;i<4;++i){
            const int row = m*16 + quad*4 + i;
            float hp = bf2f(s_h[row*LDH + n]);
            float r  = sigmoidf(ar[m][i] + pr[m][i]);
            float z  = sigmoidf(az[m][i] + pz[m][i]);
            float nn = tanh_fast(an[m][i] + r*pn[m][i]);
            s_x[row*LDH + n] = f2bf((1.f - z)*nn + z*hp);
        }
    }
    __syncthreads();

    // ---- step6: final = GRU(intra@Wi + bi, inter@Wh + bh ; inter) -> s_fin
    #pragma unroll
    for (int g = wave; g < 8; g += 4) {
        const int n = g*16 + lc;
        const float vir = bi[n], viz = bi[128+n], vin = bi[256+n];
        const float vhr = bh[n], vhz = bh[128+n], vhn = bh[256+n];
        f32x4 ar[2], az[2], an[2], pr[2], pz[2], pn[2];
        #pragma unroll
        for (int m=0;m<2;++m){
            ar[m]=(f32x4){vir,vir,vir,vir}; az[m]=(f32x4){viz,viz,viz,viz}; an[m]=(f32x4){vin,vin,vin,vin};
            pr[m]=(f32x4){vhr,vhr,vhr,vhr}; pz[m]=(f32x4){vhz,vhz,vhz,vhz}; pn[m]=(f32x4){vhn,vhn,vhn,vhn};
        }
        #pragma unroll
        for (int ks=0; ks<4; ++ks) {
            const int ko = ks*32 + kq;
            bf16x8s br = *(const bf16x8s*)(WiT + (n      )*128 + ko);
            bf16x8s bz = *(const bf16x8s*)(WiT + (n + 128)*128 + ko);
            bf16x8s bn = *(const bf16x8s*)(WiT + (n + 256)*128 + ko);
            #pragma unroll
            for (int m=0;m<2;++m){
                bf16x8s a = *(const bf16x8s*)(&s_x[(m*16+lc)*LDH + ko]);
                ar[m]=mfma16(a,br,ar[m]); az[m]=mfma16(a,bz,az[m]); an[m]=mfma16(a,bn,an[m]);
            }
        }
        #pragma unroll
        for (int ks=0; ks<4; ++ks) {
            const int ko = ks*32 + kq;
            bf16x8s br = *(const bf16x8s*)(WhT + (n      )*128 + ko);
            bf16x8s bz = *(const bf16x8s*)(WhT + (n + 128)*128 + ko);
            bf16x8s bn = *(const bf16x8s*)(WhT + (n + 256)*128 + ko);
            #pragma unroll
            for (int m=0;m<2;++m){
                bf16x8s a = *(const bf16x8s*)(&s_int[(m*16+lc)*LDH + ko]);
                pr[m]=mfma16(a,br,pr[m]); pz[m]=mfma16(a,bz,pz[m]); pn[m]=mfma16(a,bn,pn[m]);
            }
        }
        #pragma unroll
        for (int m=0;m<2;++m)
        #pragma unroll
        for (int i=0;i<4;++i){
            const int row = m*16 + quad*4 + i;
            float hp = bf2f(s_int[row*LDH + n]);
            float r  = sigmoidf(ar[m][i] + pr[m][i]);
            float z  = sigmoidf(az[m][i] + pz[m][i]);
            float nn = tanh_fast(an[m][i] + r*pn[m][i]);
            s_fin[row*LDH + n] = f2bf((1.f - z)*nn + z*hp);
        }
    }
    __syncthreads();

    // ---- step7: attention readout (float scratch lives in s_a, dead since step4)
    const int slen = seq_len[b];
    if (t < DIM) s_vn[t] = bf2f(s_fin[(slen-1)*LDH + t]);
    __syncthreads();
    if (t < DIM) {                       // q1+b2 -> s_q1
        float acc = b1[t] + b2[t];
        #pragma unroll
        for (int k8=0; k8<16; ++k8) {
            union{ uint4 q; short s[8]; } u;
            u.q = *reinterpret_cast<const uint4*>(W1T + t*128 + k8*8);
            #pragma unroll
            for (int u2=0;u2<8;++u2) acc += s_vn[k8*8+u2]*bf2f(u.s[u2]);
        }
        s_q1[t] = acc;
    }
    __syncthreads();
    // final@W2 via MFMA; alpha partials
    #pragma unroll
    for (int tl = wave; tl < 16; tl += 4) {
        const int m0 = (tl & 1)*16, nt = tl >> 1;
        const int n  = nt*16 + lc;
        f32x4 acc = {0.f,0.f,0.f,0.f};
        #pragma unroll
        for (int ks=0; ks<4; ++ks) {
            const int ko = ks*32 + kq;
            bf16x8s a  = *(const bf16x8s*)(&s_fin[(m0+lc)*LDH + ko]);
            bf16x8s bb = *(const bf16x8s*)(W2T + n*128 + ko);
            acc = mfma16(a, bb, acc);
        }
        const float qb  = s_q1[n];
        const float wqv = wq[n];
        float p[4];
        #pragma unroll
        for (int i=0;i<4;++i) p[i] = sigmoidf(acc[i] + qb) * wqv;
        #pragma unroll
        for (int off=1; off<16; off<<=1) {
            #pragma unroll
            for (int i=0;i<4;++i) p[i] += __shfl_xor(p[i], off);
        }
        if (lc == 0) {
            #pragma unroll
            for (int i=0;i<4;++i) s_red[(m0+quad*4+i)*8 + nt] = p[i];
        }
    }
    __syncthreads();
    if (t < L_SEQ) {
        float al = bq[0];
        #pragma unroll
        for (int u=0;u<8;++u) al += s_red[t*8+u];
        s_alpha[t] = (t < slen) ? al : 0.f;
    }
    __syncthreads();
    if (t < DIM) {
        float sg = 0.f;
        #pragma unroll
        for (int l=0;l<L_SEQ;++l) sg += s_alpha[l]*bf2f(s_fin[l*LDH + t]);
        s_sg[t] = sg;
    }
    __syncthreads();
    if (t < DIM) {                       // h_s = concat(vn,sg)@W3 + b3 -> bf16
        float acc = b3[t];
        #pragma unroll
        for (int k8=0; k8<16; ++k8) {
            union{ uint4 q; short s[8]; } u;
            u.q = *reinterpret_cast<const uint4*>(W3T + t*256 + k8*8);
            #pragma unroll
            for (int u2=0;u2<8;++u2) acc += s_vn[k8*8+u2]*bf2f(u.s[u2]);
        }
        #pragma unroll
        for (int k8=0; k8<16; ++k8) {
            union{ uint4 q; short s[8]; } u;
            u.q = *reinterpret_cast<const uint4*>(W3T + t*256 + 128 + k8*8);
            #pragma unroll
            for (int u2=0;u2<8;++u2) acc += s_sg[k8*8+u2]*bf2f(u.s[u2]);
        }
        hs_bf[b*DIM + t] = f2bf(acc);
    }
}

// ---------- scores = h_s @ emb^T, bf16 emb (round-4 measured-best form) ----------
// Operand swap: mfma(emb_frag, hs_frag) -> D rows run along n -> float4 stores.
// grid (782, 4); wave owns 64 m-rows (4 hoisted A-frag sets), 64 n-cols.
// Nontemporal stores: REQUIRED — out is never re-read; NT avoids dirty-L2
// writeback debt that throttles the adjacent harness fills (R7 A/B: -43 us).
__global__ __launch_bounds__(256)
void scores_bf(const short* __restrict__ hs, const short* __restrict__ embf,
               float* __restrict__ out)
{
    const int t    = threadIdx.x;
    const int wave = t >> 6;
    const int lane = t & 63;
    const int quad = lane >> 4;
    const int lc   = lane & 15;
    const int kq   = quad * 8;
    const int n0   = blockIdx.x * 64;
    const int mb   = blockIdx.y * 256 + wave*64;   // this wave's 64 rows

    bf16x8s hf[4][4];                              // hoisted hs fragments (L2-hot)
    #pragma unroll
    for (int mi=0; mi<4; ++mi)
        #pragma unroll
        for (int ks=0; ks<4; ++ks)
            hf[mi][ks] = *(const bf16x8s*)(hs + (size_t)(mb + mi*16 + lc)*DIM + ks*32 + kq);

    #pragma unroll
    for (int nt=0; nt<4; ++nt) {
        const int nr  = n0 + nt*16 + lc;
        const int nld = nr < NN ? nr : NN-1;
        bf16x8s ef[4];
        #pragma unroll
        for (int ks=0; ks<4; ++ks)
            ef[ks] = *(const bf16x8s*)(embf + (size_t)nld*DIM + ks*32 + kq);
        const int nbase = n0 + nt*16 + quad*4;     // NN % 4 == 0 -> chunk validity uniform
        #pragma unroll
        for (int mi=0; mi<4; ++mi) {
            f32x4 acc = {0.f,0.f,0.f,0.f};
            #pragma unroll
            for (int ks=0; ks<4; ++ks) acc = mfma16(ef[ks], hf[mi][ks], acc);
            if (nbase < NN) {
                // D[r=quad*4+i][c=lc] = scores[mb+mi*16+lc][n0+nt*16+quad*4+i]
                __builtin_nontemporal_store(acc,
                    reinterpret_cast<f32x4*>(&out[(size_t)(mb + mi*16 + lc)*NN + nbase]));
            }
        }
    }
}

// ---------- fallback (fp32 emb) if workspace too small for bf16 copies ----------
__global__ __launch_bounds__(256)
void scores_kernel(const short* __restrict__ hs, const float* __restrict__ emb,
                   float* __restrict__ out)
{
    const int t    = threadIdx.x;
    const int wave = t >> 6;
    const int lane = t & 63;
    const int quad = lane >> 4;
    const int lc   = lane & 15;
    const int kq   = quad * 8;
    const int n0   = blockIdx.x * 64;
    const int m0   = blockIdx.y * 64 + wave*16;

    bf16x8s af[4];
    #pragma unroll
    for (int ks=0; ks<4; ++ks)
        af[ks] = *(const bf16x8s*)(hs + (size_t)(m0 + lc)*DIM + ks*32 + kq);

    #pragma unroll
    for (int nt=0; nt<4; ++nt) {
        const int nabs = n0 + nt*16 + lc;
        const int nld  = nabs < NN ? nabs : NN-1;
        f32x4 acc = {0.f,0.f,0.f,0.f};
        #pragma unroll
        for (int ks=0; ks<4; ++ks) {
            float v[8]; ldf8(emb + (size_t)nld*DIM + ks*32 + kq, v);
            acc = mfma16(af[ks], cvt8(v), acc);
        }
        if (nabs < NN) {
            #pragma unroll
            for (int i=0;i<4;++i)
                out[(size_t)(m0 + quad*4 + i)*NN + nabs] = acc[i];
        }
    }
}

extern "C" void kernel_launch(void* const* d_in, const int* in_sizes, int n_in,
                              void* d_out, int out_size, void* d_ws, size_t ws_size,
                              hipStream_t stream)
{
    const int*   items   = (const int*)  d_in[0];
    const float* A_in    = (const float*)d_in[1];
    const float* A_out   = (const float*)d_in[2];
    const float* inter   = (const float*)d_in[3];
    const int*   seq_len = (const int*)  d_in[4];
    const float* emb     = (const float*)d_in[5];
    const float* W_in = (const float*)d_in[6],  *b_in  = (const float*)d_in[7];
    const float* W_out= (const float*)d_in[8],  *b_out = (const float*)d_in[9];
    const float* W_a  = (const float*)d_in[10], *U_h   = (const float*)d_in[11];
    const float* b_gru= (const float*)d_in[12];
    const float* Wi   = (const float*)d_in[13], *bi    = (const float*)d_in[14];
    const float* Wh   = (const float*)d_in[15], *bh    = (const float*)d_in[16];
    const float* W1   = (const float*)d_in[17], *b1    = (const float*)d_in[18];
    const float* W2   = (const float*)d_in[19], *b2    = (const float*)d_in[20];
    const float* wq   = (const float*)d_in[21], *bq    = (const float*)d_in[22];
    const float* W3   = (const float*)d_in[23], *b3    = (const float*)d_in[24];
    float* out = (float*)d_out;
    short* hs_bf = (short*)d_ws;                           // 1024*128 bf16 = 256 KB
    short* wt    = (short*)((char*)d_ws + 262144);         // 344064 bf16 = 688 KB
    short* embf  = (short*)((char*)d_ws + 1048576);        // 50000*128 bf16 = 12.8 MB

    const size_t need_bf = 1048576 + (size_t)NN*DIM*2;     // ~13.85 MB
    const bool use_bf = (ws_size >= need_bf);

    prep_kernel<<<use_bf ? 4469 : 1344, 256, 0, stream>>>(
        W_in, W_out, W_a, U_h, Wi, Wh, W1, W2, W3, wt, emb, embf);
    graph_fused<<<1024, 256, 0, stream>>>(items, A_in, A_out, inter, seq_len, emb,
        use_bf ? embf : (const short*)nullptr,
        b_in, b_out, b_gru, bi, bh, b1, b2, wq, bq, b3, wt, hs_bf);
    if (use_bf)
        scores_bf<<<dim3(782, 4), 256, 0, stream>>>(hs_bf, embf, out);
    else
        scores_kernel<<<dim3(782, 16), 256, 0, stream>>>(hs_bf, emb, out);
}

// Round 9
// 370.926 us; speedup vs baseline: 1.2018x; 1.0856x over previous
//
#include <hip/hip_runtime.h>
#include <hip/hip_bf16.h>

#define L_SEQ 32
#define DIM 128
#define NN 50000

typedef __attribute__((ext_vector_type(8))) short bf16x8s;
typedef __attribute__((ext_vector_type(4))) float f32x4;

// ---------- helpers ----------
__device__ __forceinline__ float bf2f(short s){
    union{unsigned u; float f;} v; v.u = ((unsigned)(unsigned short)s) << 16; return v.f;
}
__device__ __forceinline__ short f2bf(float x){
    union{__hip_bfloat16 h; short s;} u; u.h = __float2bfloat16(x); return u.s;
}
__device__ __forceinline__ void ldf8(const float* p, float* w){
    const float4 a = *reinterpret_cast<const float4*>(p);
    const float4 b = *reinterpret_cast<const float4*>(p+4);
    w[0]=a.x; w[1]=a.y; w[2]=a.z; w[3]=a.w;
    w[4]=b.x; w[5]=b.y; w[6]=b.z; w[7]=b.w;
}
__device__ __forceinline__ void st8bf(short* dst, const float* v){
    union{ short s[8]; uint4 q; } u;
    #pragma unroll
    for (int i=0;i<8;++i) u.s[i] = f2bf(v[i]);
    *reinterpret_cast<uint4*>(dst) = u.q;
}
__device__ __forceinline__ bf16x8s cvt8(const float* v){
    union{ short s[8]; bf16x8s b; } u;
    #pragma unroll
    for (int i=0;i<8;++i) u.s[i] = f2bf(v[i]);
    return u.b;
}
__device__ __forceinline__ float sigmoidf(float x){ return 1.0f/(1.0f+__expf(-x)); }
__device__ __forceinline__ float tanh_fast(float x){
    x = fminf(fmaxf(x, -15.f), 15.f);
    float e = __expf(2.f*x);
    return (e-1.f)/(e+1.f);
}
__device__ __forceinline__ f32x4 mfma16(bf16x8s a, bf16x8s b, f32x4 c){
    return __builtin_amdgcn_mfma_f32_16x16x32_bf16(a, b, c, 0, 0, 0);
}

// ---------- fused prologue: weight transpose->bf16 (FRAGMENT ORDER), emb->bf16 ----------
// blocks [0,1344): transp | [1344,4469): emb2bf
// wt element offsets unchanged: WinT 0 | WoutT 16384 | WaT 32768 | UhT 131072 |
// WiT 180224 | WhT 229376 | W1T 278528 | W2T 294912 | W3T 311296   total 344064
// MFMA-consumed matrices (Win,Wout,Wa,Uh,Wi,Wh,W2) stored in FRAGMENT order:
//   idx(n,k) = ((n>>4)*(K/32) + (k>>5))*512 + (((k>>3)&3)*16 + (n&15))*8 + (k&7)
// so a wave's B-fragment load is base + tile*512 + lane*8 -> one coalesced 1KB burst
// (was lane-stride K*2 B = 64 scattered cache lines per load -> the R8 latency wall).
// W1/W3 (scalar-dot users) keep [n][k] row-major.
__global__ __launch_bounds__(256)
void prep_kernel(const float* __restrict__ W_in, const float* __restrict__ W_out,
                 const float* __restrict__ W_a,  const float* __restrict__ U_h,
                 const float* __restrict__ Wi,   const float* __restrict__ Wh,
                 const float* __restrict__ W1,   const float* __restrict__ W2,
                 const float* __restrict__ W3,   short* __restrict__ wt,
                 const float* __restrict__ emb,  short* __restrict__ embf)
{
    const int blk = blockIdx.x;
    if (blk < 1344) {
        int idx = blk*256 + threadIdx.x;
        const float* src; int Rm1, lR, C, local, off; bool frag = true;
        if      (idx < 16384) { src=W_in;  local=idx;        off=0;      Rm1=127; lR=7; C=128; }
        else if (idx < 32768) { src=W_out; local=idx-16384;  off=16384;  Rm1=127; lR=7; C=128; }
        else if (idx < 131072){ src=W_a;   local=idx-32768;  off=32768;  Rm1=255; lR=8; C=384; }
        else if (idx < 180224){ src=U_h;   local=idx-131072; off=131072; Rm1=127; lR=7; C=384; }
        else if (idx < 229376){ src=Wi;    local=idx-180224; off=180224; Rm1=127; lR=7; C=384; }
        else if (idx < 278528){ src=Wh;    local=idx-229376; off=229376; Rm1=127; lR=7; C=384; }
        else if (idx < 294912){ src=W1;    local=idx-278528; off=278528; Rm1=127; lR=7; C=128; frag=false; }
        else if (idx < 311296){ src=W2;    local=idx-294912; off=294912; Rm1=127; lR=7; C=128; }
        else if (idx < 344064){ src=W3;    local=idx-311296; off=311296; Rm1=255; lR=8; C=128; frag=false; }
        else return;
        int k = local & Rm1;      // input-dim index
        int n = local >> lR;      // output-dim index
        int dst = frag
            ? ((n>>4)*((Rm1+1)>>5) + (k>>5))*512 + (((k>>3)&3)*16 + (n&15))*8 + (k&7)
            : local;
        wt[off + dst] = f2bf(src[k*C + n]);
    } else {
        const size_t idx = ((size_t)(blk-1344)*256 + threadIdx.x) * 8;   // 3125*256*8 == NN*DIM
        float v[8]; ldf8(emb + idx, v);
        st8bf(embf + idx, v);
    }
}

// ---------- fused graph kernel: one block (4 waves) per session, MFMA ----------
// LDS: s_h 8704 + s_a 16896 + s_r3 8704 + s_r4 17408 = 51712 B -> 3 blocks/CU
#define LDH 136   // 128-wide bf16 rows, +8 pad (272 B, 16B-aligned rows)
#define LDA 264   // 256-wide (+8 pad; conflict-free, 16B-aligned)
#define LDT 40    // transposed k<=32 rows (80 B, 16B-aligned)

__global__ __launch_bounds__(256)
void graph_fused(const int* __restrict__ items,
                 const float* __restrict__ A_in, const float* __restrict__ A_out,
                 const float* __restrict__ inter,
                 const int* __restrict__ seq_len,
                 const float* __restrict__ emb,
                 const short* __restrict__ embf,   // bf16 emb copy (may be null)
                 const float* __restrict__ b_in, const float* __restrict__ b_out,
                 const float* __restrict__ b_gru,
                 const float* __restrict__ bi, const float* __restrict__ bh,
                 const float* __restrict__ b1, const float* __restrict__ b2,
                 const float* __restrict__ wq, const float* __restrict__ bq,
                 const float* __restrict__ b3,
                 const short* __restrict__ wt,
                 short* __restrict__ hs_bf)
{
    const short* WinT  = wt + 0;        // frag [8 nt][4 ks][64][8]
    const short* WoutT = wt + 16384;    // frag
    const short* WaT   = wt + 32768;    // frag [24 nt][8 ks][64][8]
    const short* UhT   = wt + 131072;   // frag [24 nt][4 ks][64][8]
    const short* WiT   = wt + 180224;   // frag
    const short* WhT   = wt + 229376;   // frag
    const short* W1T   = wt + 278528;   // row-major [128][128]
    const short* W2T   = wt + 294912;   // frag [8 nt][4 ks][64][8]
    const short* W3T   = wt + 311296;   // row-major [128][256]

    __shared__ __align__(16) short s_h[32*LDH];        // h (bf16, A-layout)      8704 B
    __shared__ __align__(16) short s_a[32*LDA];        // concat(a_in,a_out)     16896 B
    __shared__ __align__(16) short s_r3[32*LDH];       // {Ain,Aout} then intra   8704 B
    __shared__ __align__(16) short s_r4[2*32*LDH];     // xT then {inter,final}  17408 B

    short* s_Ain  = s_r3;               // 32*40
    short* s_Aout = s_r3 + 32*LDT;      // 32*40
    short* s_x    = s_r3;               // intra, 32*136 (after step2)
    short* xT     = s_r4;               // 128*40 (single buffer, two passes)
    short* s_int  = s_r4;               // inter, 32*136 (after step2b)
    short* s_fin  = s_r4 + 32*LDH;      // final, 32*136
    // epilogue float scratch aliased onto s_a (s_a dead after step4)
    float* s_vn    = (float*)s_a;           // 128
    float* s_q1    = s_vn + 128;            // 128
    float* s_sg    = s_q1 + 128;            // 128
    float* s_red   = s_sg + 128;            // 256
    float* s_alpha = s_red + 256;           // 32

    const int b    = blockIdx.x;
    const int t    = threadIdx.x;
    const int wave = t >> 6;
    const int lane = t & 63;
    const int quad = lane >> 4;
    const int lc   = lane & 15;
    const int kq   = quad * 8;
    const int l8   = lane << 3;             // fragment-order lane offset (shorts)

    // ---- step0: fp32 inter prefetch to regs (committed at step3); h gather + A -> LDS
    float pre_i[2][8];
    #pragma unroll
    for (int i=0;i<2;++i) {
        int c = t + i*256;
        int l = c >> 4, k = (c & 15) * 8;
        ldf8(inter + ((size_t)b*L_SEQ + l)*DIM + k, pre_i[i]);
    }
    if (embf) {
        #pragma unroll
        for (int i=0;i<2;++i) {
            int c = t + i*256;                 // 512 chunks of 8 shorts (16 B)
            int l = c >> 4, k = (c & 15) * 8;
            int it = items[b*L_SEQ + l];
            *reinterpret_cast<uint4*>(&s_h[l*LDH + k]) =
                *reinterpret_cast<const uint4*>(embf + (size_t)it*DIM + k);
        }
    } else {
        #pragma unroll
        for (int i=0;i<2;++i) {
            int c = t + i*256;
            int l = c >> 4, k = (c & 15) * 8;
            int it = items[b*L_SEQ + l];
            float v[8]; ldf8(emb + (size_t)it*DIM + k, v);
            st8bf(&s_h[l*LDH + k], v);
        }
    }
    {
        const int which = t >> 7;
        const int rem   = t & 127;
        const int l = rem >> 2, m = (rem & 3) * 8;
        const float* src = which ? A_out : A_in;
        float v[8]; ldf8(src + b*L_SEQ*L_SEQ + l*L_SEQ + m, v);
        st8bf((which ? s_Aout : s_Ain) + l*LDT + m, v);
    }
    __syncthreads();

    // ---- step1/step2 two passes over op (shared xT buffer)
    #pragma unroll
    for (int op = 0; op < 2; ++op) {
        // step1: h @ {W_in|W_out} + bias -> xT[n][k]
        const short* WT_ = op ? WoutT : WinT;
        #pragma unroll
        for (int p = 0; p < 2; ++p) {
            const int nt = wave*2 + p;
            const int n  = nt*16 + lc;
            const float bv = op ? b_out[n] : b_in[n];
            f32x4 acc0 = {bv,bv,bv,bv}, acc1 = {bv,bv,bv,bv};
            #pragma unroll
            for (int ks = 0; ks < 4; ++ks) {
                const int ko = ks*32 + kq;
                bf16x8s bb = *(const bf16x8s*)(WT_ + ((nt*4 + ks)<<9) + l8);
                bf16x8s a0 = *(const bf16x8s*)(&s_h[(lc   )*LDH + ko]);
                bf16x8s a1 = *(const bf16x8s*)(&s_h[(16+lc)*LDH + ko]);
                acc0 = mfma16(a0, bb, acc0);
                acc1 = mfma16(a1, bb, acc1);
            }
            union{short s[4]; unsigned long long q;} u0, u1;
            #pragma unroll
            for (int i=0;i<4;++i){ u0.s[i]=f2bf(acc0[i]); u1.s[i]=f2bf(acc1[i]); }
            *(unsigned long long*)(&xT[n*LDT + 0  + quad*4]) = u0.q;
            *(unsigned long long*)(&xT[n*LDT + 16 + quad*4]) = u1.q;
        }
        __syncthreads();
        // step2: {A_in|A_out} @ xT -> s_a half (K=32, one MFMA per unit)
        const short* Abuf = op ? s_Aout : s_Ain;
        #pragma unroll
        for (int u = 0; u < 4; ++u) {
            int unit = wave*4 + u;             // 0..15
            int nt = unit >> 1, m0 = (unit & 1)*16;
            bf16x8s a  = *(const bf16x8s*)(&Abuf[(m0+lc)*LDT + kq]);
            bf16x8s bb = *(const bf16x8s*)(&xT[(nt*16+lc)*LDT + kq]);
            f32x4 acc = {0.f,0.f,0.f,0.f};
            acc = mfma16(a, bb, acc);
            #pragma unroll
            for (int i=0;i<4;++i)
                s_a[(m0+quad*4+i)*LDA + op*128 + nt*16 + lc] = f2bf(acc[i]);
        }
        __syncthreads();
    }

    // ---- step3: commit prefetched inter -> s_int (xT dead after last barrier)
    #pragma unroll
    for (int i=0;i<2;++i) {
        int c = t + i*256;
        int l = c >> 4, k = (c & 15) * 8;
        st8bf(&s_int[l*LDH + k], pre_i[i]);
    }

    // ---- step4: intra = GRU(a@W_a + b_gru, h@U_h ; h) -> s_x
    #pragma unroll
    for (int g = wave; g < 8; g += 4) {
        const int n = g*16 + lc;
        const float vr = b_gru[n], vz = b_gru[128+n], vn2 = b_gru[256+n];
        f32x4 ar[2], az[2], an[2], pr[2], pz[2], pn[2];
        #pragma unroll
        for (int m=0;m<2;++m){
            ar[m]=(f32x4){vr,vr,vr,vr}; az[m]=(f32x4){vz,vz,vz,vz}; an[m]=(f32x4){vn2,vn2,vn2,vn2};
            pr[m]=(f32x4){0,0,0,0}; pz[m]=pr[m]; pn[m]=pr[m];
        }
        #pragma unroll
        for (int ks=0; ks<8; ++ks) {
            const int ko = ks*32 + kq;
            bf16x8s br = *(const bf16x8s*)(WaT + (((g     )*8 + ks)<<9) + l8);
            bf16x8s bz = *(const bf16x8s*)(WaT + (((g +  8)*8 + ks)<<9) + l8);
            bf16x8s bn = *(const bf16x8s*)(WaT + (((g + 16)*8 + ks)<<9) + l8);
            #pragma unroll
            for (int m=0;m<2;++m){
                bf16x8s a = *(const bf16x8s*)(&s_a[(m*16+lc)*LDA + ko]);
                ar[m]=mfma16(a,br,ar[m]); az[m]=mfma16(a,bz,az[m]); an[m]=mfma16(a,bn,an[m]);
            }
        }
        #pragma unroll
        for (int ks=0; ks<4; ++ks) {
            const int ko = ks*32 + kq;
            bf16x8s br = *(const bf16x8s*)(UhT + (((g     )*4 + ks)<<9) + l8);
            bf16x8s bz = *(const bf16x8s*)(UhT + (((g +  8)*4 + ks)<<9) + l8);
            bf16x8s bn = *(const bf16x8s*)(UhT + (((g + 16)*4 + ks)<<9) + l8);
            #pragma unroll
            for (int m=0;m<2;++m){
                bf16x8s a = *(const bf16x8s*)(&s_h[(m*16+lc)*LDH + ko]);
                pr[m]=mfma16(a,br,pr[m]); pz[m]=mfma16(a,bz,pz[m]); pn[m]=mfma16(a,bn,pn[m]);
            }
        }
        #pragma unroll
        for (int m=0;m<2;++m)
        #pragma unroll
        for (int i=0;i<4;++i){
            const int row = m*16 + quad*4 + i;
            float hp = bf2f(s_h[row*LDH + n]);
            float r  = sigmoidf(ar[m][i] + pr[m][i]);
            float z  = sigmoidf(az[m][i] + pz[m][i]);
            float nn = tanh_fast(an[m][i] + r*pn[m][i]);
            s_x[row*LDH + n] = f2bf((1.f - z)*nn + z*hp);
        }
    }
    __syncthreads();

    // ---- step6: final = GRU(intra@Wi + bi, inter@Wh + bh ; inter) -> s_fin
    #pragma unroll
    for (int g = wave; g < 8; g += 4) {
        const int n = g*16 + lc;
        const float vir = bi[n], viz = bi[128+n], vin = bi[256+n];
        const float vhr = bh[n], vhz = bh[128+n], vhn = bh[256+n];
        f32x4 ar[2], az[2], an[2], pr[2], pz[2], pn[2];
        #pragma unroll
        for (int m=0;m<2;++m){
            ar[m]=(f32x4){vir,vir,vir,vir}; az[m]=(f32x4){viz,viz,viz,viz}; an[m]=(f32x4){vin,vin,vin,vin};
            pr[m]=(f32x4){vhr,vhr,vhr,vhr}; pz[m]=(f32x4){vhz,vhz,vhz,vhz}; pn[m]=(f32x4){vhn,vhn,vhn,vhn};
        }
        #pragma unroll
        for (int ks=0; ks<4; ++ks) {
            const int ko = ks*32 + kq;
            bf16x8s br = *(const bf16x8s*)(WiT + (((g     )*4 + ks)<<9) + l8);
            bf16x8s bz = *(const bf16x8s*)(WiT + (((g +  8)*4 + ks)<<9) + l8);
            bf16x8s bn = *(const bf16x8s*)(WiT + (((g + 16)*4 + ks)<<9) + l8);
            #pragma unroll
            for (int m=0;m<2;++m){
                bf16x8s a = *(const bf16x8s*)(&s_x[(m*16+lc)*LDH + ko]);
                ar[m]=mfma16(a,br,ar[m]); az[m]=mfma16(a,bz,az[m]); an[m]=mfma16(a,bn,an[m]);
            }
        }
        #pragma unroll
        for (int ks=0; ks<4; ++ks) {
            const int ko = ks*32 + kq;
            bf16x8s br = *(const bf16x8s*)(WhT + (((g     )*4 + ks)<<9) + l8);
            bf16x8s bz = *(const bf16x8s*)(WhT + (((g +  8)*4 + ks)<<9) + l8);
            bf16x8s bn = *(const bf16x8s*)(WhT + (((g + 16)*4 + ks)<<9) + l8);
            #pragma unroll
            for (int m=0;m<2;++m){
                bf16x8s a = *(const bf16x8s*)(&s_int[(m*16+lc)*LDH + ko]);
                pr[m]=mfma16(a,br,pr[m]); pz[m]=mfma16(a,bz,pz[m]); pn[m]=mfma16(a,bn,pn[m]);
            }
        }
        #pragma unroll
        for (int m=0;m<2;++m)
        #pragma unroll
        for (int i=0;i<4;++i){
            const int row = m*16 + quad*4 + i;
            float hp = bf2f(s_int[row*LDH + n]);
            float r  = sigmoidf(ar[m][i] + pr[m][i]);
            float z  = sigmoidf(az[m][i] + pz[m][i]);
            float nn = tanh_fast(an[m][i] + r*pn[m][i]);
            s_fin[row*LDH + n] = f2bf((1.f - z)*nn + z*hp);
        }
    }
    __syncthreads();

    // ---- step7: attention readout (float scratch lives in s_a, dead since step4)
    const int slen = seq_len[b];
    if (t < DIM) s_vn[t] = bf2f(s_fin[(slen-1)*LDH + t]);
    __syncthreads();
    if (t < DIM) {                       // q1+b2 -> s_q1 (W1T row-major, scalar dot)
        float acc = b1[t] + b2[t];
        #pragma unroll
        for (int k8=0; k8<16; ++k8) {
            union{ uint4 q; short s[8]; } u;
            u.q = *reinterpret_cast<const uint4*>(W1T + t*128 + k8*8);
            #pragma unroll
            for (int u2=0;u2<8;++u2) acc += s_vn[k8*8+u2]*bf2f(u.s[u2]);
        }
        s_q1[t] = acc;
    }
    __syncthreads();
    // final@W2 via MFMA (W2T fragment order); alpha partials
    #pragma unroll
    for (int tl = wave; tl < 16; tl += 4) {
        const int m0 = (tl & 1)*16, nt = tl >> 1;
        const int n  = nt*16 + lc;
        f32x4 acc = {0.f,0.f,0.f,0.f};
        #pragma unroll
        for (int ks=0; ks<4; ++ks) {
            const int ko = ks*32 + kq;
            bf16x8s a  = *(const bf16x8s*)(&s_fin[(m0+lc)*LDH + ko]);
            bf16x8s bb = *(const bf16x8s*)(W2T + ((nt*4 + ks)<<9) + l8);
            acc = mfma16(a, bb, acc);
        }
        const float qb  = s_q1[n];
        const float wqv = wq[n];
        float p[4];
        #pragma unroll
        for (int i=0;i<4;++i) p[i] = sigmoidf(acc[i] + qb) * wqv;
        #pragma unroll
        for (int off=1; off<16; off<<=1) {
            #pragma unroll
            for (int i=0;i<4;++i) p[i] += __shfl_xor(p[i], off);
        }
        if (lc == 0) {
            #pragma unroll
            for (int i=0;i<4;++i) s_red[(m0+quad*4+i)*8 + nt] = p[i];
        }
    }
    __syncthreads();
    if (t < L_SEQ) {
        float al = bq[0];
        #pragma unroll
        for (int u=0;u<8;++u) al += s_red[t*8+u];
        s_alpha[t] = (t < slen) ? al : 0.f;
    }
    __syncthreads();
    if (t < DIM) {
        float sg = 0.f;
        #pragma unroll
        for (int l=0;l<L_SEQ;++l) sg += s_alpha[l]*bf2f(s_fin[l*LDH + t]);
        s_sg[t] = sg;
    }
    __syncthreads();
    if (t < DIM) {                       // h_s = concat(vn,sg)@W3 + b3 -> bf16 (W3T row-major)
        float acc = b3[t];
        #pragma unroll
        for (int k8=0; k8<16; ++k8) {
            union{ uint4 q; short s[8]; } u;
            u.q = *reinterpret_cast<const uint4*>(W3T + t*256 + k8*8);
            #pragma unroll
            for (int u2=0;u2<8;++u2) acc += s_vn[k8*8+u2]*bf2f(u.s[u2]);
        }
        #pragma unroll
        for (int k8=0; k8<16; ++k8) {
            union{ uint4 q; short s[8]; } u;
            u.q = *reinterpret_cast<const uint4*>(W3T + t*256 + 128 + k8*8);
            #pragma unroll
            for (int u2=0;u2<8;++u2) acc += s_sg[k8*8+u2]*bf2f(u.s[u2]);
        }
        hs_bf[b*DIM + t] = f2bf(acc);
    }
}

// ---------- scores = h_s @ emb^T, bf16 emb (round-4 measured-best form) ----------
// Operand swap: mfma(emb_frag, hs_frag) -> D rows run along n -> float4 stores.
// grid (782, 4); wave owns 64 m-rows (4 hoisted A-frag sets), 64 n-cols.
// Nontemporal stores: REQUIRED — out is never re-read; NT avoids dirty-L2
// writeback debt that throttles the adjacent harness fills (R7 A/B: -43 us).
__global__ __launch_bounds__(256)
void scores_bf(const short* __restrict__ hs, const short* __restrict__ embf,
               float* __restrict__ out)
{
    const int t    = threadIdx.x;
    const int wave = t >> 6;
    const int lane = t & 63;
    const int quad = lane >> 4;
    const int lc   = lane & 15;
    const int kq   = quad * 8;
    const int n0   = blockIdx.x * 64;
    const int mb   = blockIdx.y * 256 + wave*64;   // this wave's 64 rows

    bf16x8s hf[4][4];                              // hoisted hs fragments (L2-hot)
    #pragma unroll
    for (int mi=0; mi<4; ++mi)
        #pragma unroll
        for (int ks=0; ks<4; ++ks)
            hf[mi][ks] = *(const bf16x8s*)(hs + (size_t)(mb + mi*16 + lc)*DIM + ks*32 + kq);

    #pragma unroll
    for (int nt=0; nt<4; ++nt) {
        const int nr  = n0 + nt*16 + lc;
        const int nld = nr < NN ? nr : NN-1;
        bf16x8s ef[4];
        #pragma unroll
        for (int ks=0; ks<4; ++ks)
            ef[ks] = *(const bf16x8s*)(embf + (size_t)nld*DIM + ks*32 + kq);
        const int nbase = n0 + nt*16 + quad*4;     // NN % 4 == 0 -> chunk validity uniform
        #pragma unroll
        for (int mi=0; mi<4; ++mi) {
            f32x4 acc = {0.f,0.f,0.f,0.f};
            #pragma unroll
            for (int ks=0; ks<4; ++ks) acc = mfma16(ef[ks], hf[mi][ks], acc);
            if (nbase < NN) {
                // D[r=quad*4+i][c=lc] = scores[mb+mi*16+lc][n0+nt*16+quad*4+i]
                __builtin_nontemporal_store(acc,
                    reinterpret_cast<f32x4*>(&out[(size_t)(mb + mi*16 + lc)*NN + nbase]));
            }
        }
    }
}

// ---------- fallback (fp32 emb) if workspace too small for bf16 copies ----------
__global__ __launch_bounds__(256)
void scores_kernel(const short* __restrict__ hs, const float* __restrict__ emb,
                   float* __restrict__ out)
{
    const int t    = threadIdx.x;
    const int wave = t >> 6;
    const int lane = t & 63;
    const int quad = lane >> 4;
    const int lc   = lane & 15;
    const int kq   = quad * 8;
    const int n0   = blockIdx.x * 64;
    const int m0   = blockIdx.y * 64 + wave*16;

    bf16x8s af[4];
    #pragma unroll
    for (int ks=0; ks<4; ++ks)
        af[ks] = *(const bf16x8s*)(hs + (size_t)(m0 + lc)*DIM + ks*32 + kq);

    #pragma unroll
    for (int nt=0; nt<4; ++nt) {
        const int nabs = n0 + nt*16 + lc;
        const int nld  = nabs < NN ? nabs : NN-1;
        f32x4 acc = {0.f,0.f,0.f,0.f};
        #pragma unroll
        for (int ks=0; ks<4; ++ks) {
            float v[8]; ldf8(emb + (size_t)nld*DIM + ks*32 + kq, v);
            acc = mfma16(af[ks], cvt8(v), acc);
        }
        if (nabs < NN) {
            #pragma unroll
            for (int i=0;i<4;++i)
                out[(size_t)(m0 + quad*4 + i)*NN + nabs] = acc[i];
        }
    }
}

extern "C" void kernel_launch(void* const* d_in, const int* in_sizes, int n_in,
                              void* d_out, int out_size, void* d_ws, size_t ws_size,
                              hipStream_t stream)
{
    const int*   items   = (const int*)  d_in[0];
    const float* A_in    = (const float*)d_in[1];
    const float* A_out   = (const float*)d_in[2];
    const float* inter   = (const float*)d_in[3];
    const int*   seq_len = (const int*)  d_in[4];
    const float* emb     = (const float*)d_in[5];
    const float* W_in = (const float*)d_in[6],  *b_in  = (const float*)d_in[7];
    const float* W_out= (const float*)d_in[8],  *b_out = (const float*)d_in[9];
    const float* W_a  = (const float*)d_in[10], *U_h   = (const float*)d_in[11];
    const float* b_gru= (const float*)d_in[12];
    const float* Wi   = (const float*)d_in[13], *bi    = (const float*)d_in[14];
    const float* Wh   = (const float*)d_in[15], *bh    = (const float*)d_in[16];
    const float* W1   = (const float*)d_in[17], *b1    = (const float*)d_in[18];
    const float* W2   = (const float*)d_in[19], *b2    = (const float*)d_in[20];
    const float* wq   = (const float*)d_in[21], *bq    = (const float*)d_in[22];
    const float* W3   = (const float*)d_in[23], *b3    = (const float*)d_in[24];
    float* out = (float*)d_out;
    short* hs_bf = (short*)d_ws;                           // 1024*128 bf16 = 256 KB
    short* wt    = (short*)((char*)d_ws + 262144);         // 344064 bf16 = 688 KB
    short* embf  = (short*)((char*)d_ws + 1048576);        // 50000*128 bf16 = 12.8 MB

    const size_t need_bf = 1048576 + (size_t)NN*DIM*2;     // ~13.85 MB
    const bool use_bf = (ws_size >= need_bf);

    prep_kernel<<<use_bf ? 4469 : 1344, 256, 0, stream>>>(
        W_in, W_out, W_a, U_h, Wi, Wh, W1, W2, W3, wt, emb, embf);
    graph_fused<<<1024, 256, 0, stream>>>(items, A_in, A_out, inter, seq_len, emb,
        use_bf ? embf : (const short*)nullptr,
        b_in, b_out, b_gru, bi, bh, b1, b2, wq, bq, b3, wt, hs_bf);
    if (use_bf)
        scores_bf<<<dim3(782, 4), 256, 0, stream>>>(hs_bf, embf, out);
    else
        scores_kernel<<<dim3(782, 16), 256, 0, stream>>>(hs_bf, emb, out);
}